// Round 1
// 338.302 us; speedup vs baseline: 1.0640x; 1.0640x over previous
//
#include <hip/hip_runtime.h>
#include <hip/hip_bf16.h>

#define HID 64
#define INDIM 128
#define BK_SHIFT 7            // 128 nodes per bucket
#define BK_NODES 128
#define NBK_MAX 1024          // supports N <= 131072
#define PB_BLOCKS 512
#define PB_MAXI 16            // supports E <= 512*256*16 = 2.097M
#define WT_STRIDE 65          // (lane+c) mod 32 banking -> 2-way only (free, m136)

// ---------- CSR build: fixed-capacity buckets ----------

__global__ __launch_bounds__(256) void cinit_k(int* __restrict__ cursor, int nb, int cap) {
    int b = blockIdx.x * 256 + threadIdx.x;
    if (b < nb) cursor[b] = b * cap;
}

// partition edges into fixed-capacity bucket regions; packed entry = src | ldst<<20
__global__ __launch_bounds__(256) void bpart_k(const int* __restrict__ src,
                                               const int* __restrict__ dst,
                                               int* __restrict__ cursor,
                                               int* __restrict__ bucketed, int E, int cap) {
    __shared__ int hist[NBK_MAX];
    __shared__ int base[NBK_MAX];
    for (int i = threadIdx.x; i < NBK_MAX; i += 256) hist[i] = 0;
    __syncthreads();
    int code[PB_MAXI];
#pragma unroll
    for (int i = 0; i < PB_MAXI; i++) {
        code[i] = -1;
        long e = (long)i * (PB_BLOCKS * 256) + (long)blockIdx.x * 256 + threadIdx.x;
        if (e < E) {
            int b = dst[e] >> BK_SHIFT;
            int p = atomicAdd(&hist[b], 1);   // p < 4096 (block edge total)
            code[i] = (b << 12) | p;
        }
    }
    __syncthreads();
    for (int i = threadIdx.x; i < NBK_MAX; i += 256)
        base[i] = hist[i] ? atomicAdd(&cursor[i], hist[i]) : 0;
    __syncthreads();
#pragma unroll
    for (int i = 0; i < PB_MAXI; i++) {
        long e = (long)i * (PB_BLOCKS * 256) + (long)blockIdx.x * 256 + threadIdx.x;
        if (e < E) {
            int b = code[i] >> 12, p = code[i] & 0xFFF;
            int pos = base[b] + p;
            if (pos < (b + 1) * cap)          // overflow guard (never hit for random dst)
                bucketed[pos] = src[e] | ((dst[e] & (BK_NODES - 1)) << 20);
        }
    }
}

// one block per 128-node bucket: counting sort; emits rowbeg/rowend + dinv
__global__ __launch_bounds__(256) void bsort_k(const int* __restrict__ bucketed,
                                               const int* __restrict__ cursor,
                                               int* __restrict__ rowbeg,
                                               int* __restrict__ rowend,
                                               int* __restrict__ sorted_src,
                                               float* __restrict__ dinv, int N, int cap) {
    __shared__ int deg[BK_NODES];
    __shared__ int scn[BK_NODES];
    __shared__ int cur[BK_NODES];
    int b = blockIdx.x, t = threadIdx.x;
    int nstart = b << BK_SHIFT;
    int ncnt = min(BK_NODES, N - nstart);
    int estart = b * cap;
    int ecnt = cursor[b] - estart;            // final cursor = base + count
    if (t < BK_NODES) deg[t] = 0;
    __syncthreads();
    for (int j = t; j < ecnt; j += 256)
        atomicAdd(&deg[bucketed[estart + j] >> 20], 1);
    __syncthreads();
    int myv = (t < BK_NODES) ? deg[t] : 0;
    if (t < BK_NODES) scn[t] = myv;
    __syncthreads();
    for (int off = 1; off < BK_NODES; off <<= 1) {
        int x = (t < BK_NODES && t >= off) ? scn[t - off] : 0;
        __syncthreads();
        if (t < BK_NODES) scn[t] += x;
        __syncthreads();
    }
    if (t < ncnt) {
        int excl = scn[t] - myv;
        rowbeg[nstart + t] = estart + excl;
        rowend[nstart + t] = estart + scn[t];
        dinv[nstart + t] = rsqrtf(1.0f + (float)myv);  // self-loop + in-degree
        cur[t] = excl;
    }
    __syncthreads();
    for (int j = t; j < ecnt; j += 256) {
        int eg = bucketed[estart + j];
        int p = atomicAdd(&cur[eg >> 20], 1);
        sorted_src[estart + p] = eg & 0xFFFFF;
    }
}

// ---------- compute ----------

// hs1[M,64] = ((x[M,128] @ W1) * dinv) in bf16. Thread-per-row, W in LDS.
__global__ __launch_bounds__(256) void gemm1_k(const float* __restrict__ A,
                                               const float* __restrict__ W,
                                               const float* __restrict__ dinv,
                                               __hip_bfloat16* __restrict__ C, int M) {
    __shared__ float lw[INDIM * HID];
    for (int i = threadIdx.x; i < INDIM * HID / 4; i += 256)
        ((float4*)lw)[i] = ((const float4*)W)[i];
    __syncthreads();
    int row = blockIdx.x * 256 + threadIdx.x;
    if (row >= M) return;
    float acc[HID];
#pragma unroll
    for (int c = 0; c < HID; c++) acc[c] = 0.0f;
    const float* a = A + (long)row * INDIM;
    for (int k = 0; k < INDIM; k += 4) {
        float4 v = *(const float4*)(a + k);
        float av[4] = {v.x, v.y, v.z, v.w};
#pragma unroll
        for (int kk = 0; kk < 4; kk++) {
            const float4* wr = (const float4*)(lw + (k + kk) * HID);
#pragma unroll
            for (int c4 = 0; c4 < 16; c4++) {
                float4 w = wr[c4];
                acc[4 * c4 + 0] = fmaf(av[kk], w.x, acc[4 * c4 + 0]);
                acc[4 * c4 + 1] = fmaf(av[kk], w.y, acc[4 * c4 + 1]);
                acc[4 * c4 + 2] = fmaf(av[kk], w.z, acc[4 * c4 + 2]);
                acc[4 * c4 + 3] = fmaf(av[kk], w.w, acc[4 * c4 + 3]);
            }
        }
    }
    float s = dinv[row];
    __hip_bfloat16* out = C + (long)row * HID;
#pragma unroll
    for (int c = 0; c < HID; c += 8) {
        union { uint4 u; __hip_bfloat16 h[8]; } p;
#pragma unroll
        for (int j = 0; j < 8; j++) p.h[j] = __float2bfloat16(acc[c + j] * s);
        *(uint4*)(out + c) = p.u;
    }
}

#define BCAST(r, c) __int_as_float(__builtin_amdgcn_readlane(__float_as_int(r), (c)))

// unpack one dword-pair (4 bf16 features) and accumulate into a0..a3, exact f32 math
#define ACC4(v)                                            \
    do {                                                   \
        a0 += __uint_as_float((v).x << 16);                \
        a1 += __uint_as_float((v).x & 0xffff0000u);        \
        a2 += __uint_as_float((v).y << 16);                \
        a3 += __uint_as_float((v).y & 0xffff0000u);        \
    } while (0)

// fused gather + next-layer GEMM. Wave per node.
// Gather layout: 16 lanes x dwordx2 (4 bf16 features/lane) per row, so FOUR edges are
// processed per wave-instruction: g = lane>>4 picks the edge sub-stream, fo = 4*(lane&15)
// picks the feature quad. Per edge: ~0.25 row loads, ~0.25 idx loads, ~0.75 addr VALU,
// 2 accumulate VALU (vs ~7 VALU + 2 VMEM in the lane-per-feature layout).
// Tail = ONE clamped 16-edge block (all loads issued in parallel, chain depth 1).
// Butterfly shfl_xor(16,32) merges the 4 sub-streams; then the same conflict-free
// stride-65 readlane FC (output feature = lane), broadcasting r[f&3] from lane f>>2.
template <bool HS_OUT>
__global__ __launch_bounds__(256) void fgather_k(void* __restrict__ outp,
                                                 const __hip_bfloat16* __restrict__ hs,
                                                 const float* __restrict__ dinv,
                                                 const float* __restrict__ biasA,
                                                 const float* __restrict__ Wn,
                                                 const float* __restrict__ biasB,
                                                 const int* __restrict__ rowbeg,
                                                 const int* __restrict__ rowend,
                                                 const int* __restrict__ sorted_src, int n) {
    __shared__ float lwt[HID * WT_STRIDE];
    for (int i = threadIdx.x; i < HID * HID; i += 256) {
        int c = i >> 6, l = i & 63;
        lwt[l * WT_STRIDE + c] = Wn[i];      // transpose: lane-major, stride 65
    }
    __syncthreads();
    int node = blockIdx.x * 4 + (threadIdx.x >> 6);
    int lane = threadIdx.x & 63;
    if (node >= n) return;                   // whole wave exits together
    int g = lane >> 4;                       // edge sub-stream 0..3
    int fo = (lane & 15) << 2;               // feature offset 0,4,...,60
    int e0 = rowbeg[node], e1 = rowend[node];
    float a0 = 0.f, a1 = 0.f, a2 = 0.f, a3 = 0.f;
    int e = e0;
    // main: 16 edges per iteration, no clamping
    for (; e + 16 <= e1; e += 16) {
        int i0 = sorted_src[e + g];
        int i1 = sorted_src[e + 4 + g];
        int i2 = sorted_src[e + 8 + g];
        int i3 = sorted_src[e + 12 + g];
        uint2 v0 = *(const uint2*)(hs + ((i0 << 6) + fo));
        uint2 v1 = *(const uint2*)(hs + ((i1 << 6) + fo));
        uint2 v2 = *(const uint2*)(hs + ((i2 << 6) + fo));
        uint2 v3 = *(const uint2*)(hs + ((i3 << 6) + fo));
        ACC4(v0); ACC4(v1); ACC4(v2); ACC4(v3);
    }
    // tail: one clamped 16-edge block (covers rem = 1..15), all loads in flight at once
    if (e < e1) {
        int last = e1 - 1;
        int m0 = e + g, m1 = m0 + 4, m2 = m0 + 8, m3 = m0 + 12;
        int i0 = sorted_src[m0 <= last ? m0 : last];
        int i1 = sorted_src[m1 <= last ? m1 : last];
        int i2 = sorted_src[m2 <= last ? m2 : last];
        int i3 = sorted_src[m3 <= last ? m3 : last];
        uint2 v0 = *(const uint2*)(hs + ((i0 << 6) + fo));
        uint2 v1 = *(const uint2*)(hs + ((i1 << 6) + fo));
        uint2 v2 = *(const uint2*)(hs + ((i2 << 6) + fo));
        uint2 v3 = *(const uint2*)(hs + ((i3 << 6) + fo));
        if (m0 > last) { v0.x = 0u; v0.y = 0u; }
        if (m1 > last) { v1.x = 0u; v1.y = 0u; }
        if (m2 > last) { v2.x = 0u; v2.y = 0u; }
        if (m3 > last) { v3.x = 0u; v3.y = 0u; }
        ACC4(v0); ACC4(v1); ACC4(v2); ACC4(v3);
    }
    // merge the 4 edge sub-streams (feature class l&15 preserved by xor 16/32)
    a0 += __shfl_xor(a0, 16); a1 += __shfl_xor(a1, 16);
    a2 += __shfl_xor(a2, 16); a3 += __shfl_xor(a3, 16);
    a0 += __shfl_xor(a0, 32); a1 += __shfl_xor(a1, 32);
    a2 += __shfl_xor(a2, 32); a3 += __shfl_xor(a3, 32);
    // self-loop term (same quad layout)
    {
        uint2 sv = *(const uint2*)(hs + ((node << 6) + fo));
        ACC4(sv);
    }
    float di = dinv[node];
    float4 bb = *(const float4*)(biasA + fo);
    float r0 = fmaxf(fmaf(di, a0, bb.x), 0.0f);
    float r1 = fmaxf(fmaf(di, a1, bb.y), 0.0f);
    float r2 = fmaxf(fmaf(di, a2, bb.z), 0.0f);
    float r3 = fmaxf(fmaf(di, a3, bb.w), 0.0f);
    // FC: output feature = lane. Feature f lives in r[f&3] of lane f>>2.
    float o0 = HS_OUT ? 0.0f : biasB[lane];
    float o1 = 0.f, o2 = 0.f, o3 = 0.f;
    const float* wl = lwt + lane * WT_STRIDE;
#pragma unroll
    for (int f = 0; f < HID; f += 4) {
        int sl = f >> 2;                     // constant source lane 0..15 after unroll
        float w0 = wl[f], w1 = wl[f + 1], w2 = wl[f + 2], w3 = wl[f + 3];
        o0 = fmaf(BCAST(r0, sl), w0, o0);
        o1 = fmaf(BCAST(r1, sl), w1, o1);
        o2 = fmaf(BCAST(r2, sl), w2, o2);
        o3 = fmaf(BCAST(r3, sl), w3, o3);
    }
    float o = (o0 + o1) + (o2 + o3);
    if (HS_OUT)
        ((__hip_bfloat16*)outp)[(node << 6) + lane] = __float2bfloat16(o * di);
    else
        ((float*)outp)[(node << 6) + lane] = o;
}

extern "C" void kernel_launch(void* const* d_in, const int* in_sizes, int n_in,
                              void* d_out, int out_size, void* d_ws, size_t ws_size,
                              hipStream_t stream) {
    const float* x   = (const float*)d_in[0];
    const int*   ei  = (const int*)d_in[1];
    const float* W1  = (const float*)d_in[2];
    const float* b1  = (const float*)d_in[3];
    const float* W2  = (const float*)d_in[4];
    const float* b2  = (const float*)d_in[5];
    const float* Wfc = (const float*)d_in[6];
    const float* bfc = (const float*)d_in[7];

    int N = in_sizes[0] / INDIM;
    int E = in_sizes[1] / 2;
    const int* src = ei;       // edge_index row 0
    const int* dst = ei + E;   // edge_index row 1
    int nb = (N + BK_NODES - 1) >> BK_SHIFT;          // 782 buckets
    int cap = (2 * E / nb + 63) & ~63;                // 2x mean bucket load
    if (cap < 4096) cap = 4096;

    char* ws = (char*)d_ws;
    auto alloc = [&](size_t bytes) {
        char* p = ws;
        ws += (bytes + 15) & ~(size_t)15;
        return p;
    };
    int*   rowbeg     = (int*)alloc(sizeof(int) * (size_t)N);
    int*   rowend     = (int*)alloc(sizeof(int) * (size_t)N);
    float* dinv       = (float*)alloc(sizeof(float) * (size_t)N);
    int*   cursor     = (int*)alloc(sizeof(int) * NBK_MAX);
    int*   sorted_src = (int*)alloc(sizeof(int) * (size_t)nb * cap);
    // big region: bucketed (int, nb*cap) first; later hs1+hs2 (bf16, 2*N*64).
    size_t big_bytes = sizeof(int) * (size_t)nb * cap;
    size_t hs_bytes  = sizeof(__hip_bfloat16) * 2 * (size_t)N * HID;
    char*  big       = alloc(big_bytes > hs_bytes ? big_bytes : hs_bytes);
    int*   bucketed  = (int*)big;
    __hip_bfloat16* hs1 = (__hip_bfloat16*)big;
    __hip_bfloat16* hs2 = hs1 + (size_t)N * HID;
    float* outp      = (float*)d_out;

    // build: 3 dispatches
    cinit_k<<<(nb + 255) / 256, 256, 0, stream>>>(cursor, nb, cap);
    bpart_k<<<PB_BLOCKS, 256, 0, stream>>>(src, dst, cursor, bucketed, E, cap);
    bsort_k<<<nb, 256, 0, stream>>>(bucketed, cursor, rowbeg, rowend, sorted_src, dinv, N, cap);

    // compute: 3 dispatches
    gemm1_k<<<(N + 255) / 256, 256, 0, stream>>>(x, W1, dinv, hs1, N);
    fgather_k<true><<<(N + 3) / 4, 256, 0, stream>>>(hs2, hs1, dinv, b1, W2, nullptr,
                                                     rowbeg, rowend, sorted_src, N);
    fgather_k<false><<<(N + 3) / 4, 256, 0, stream>>>(outp, hs2, dinv, b2, Wfc, bfc,
                                                      rowbeg, rowend, sorted_src, N);
}

// Round 2
// 306.363 us; speedup vs baseline: 1.1749x; 1.1043x over previous
//
#include <hip/hip_runtime.h>
#include <hip/hip_bf16.h>

#define HID 64
#define INDIM 128
#define BK_SHIFT 7            // 128 nodes per bucket
#define BK_NODES 128
#define NBK_MAX 1024          // supports N <= 131072
#define PB_BLOCKS 512
#define PB_MAXI 16            // supports E <= 512*256*16 = 2.097M

typedef __attribute__((ext_vector_type(8))) short bf16x8;
typedef __attribute__((ext_vector_type(4))) float f32x4;

// ---------- CSR build: fixed-capacity buckets ----------

__global__ __launch_bounds__(256) void cinit_k(int* __restrict__ cursor, int nb, int cap) {
    int b = blockIdx.x * 256 + threadIdx.x;
    if (b < nb) cursor[b] = b * cap;
}

// partition edges into fixed-capacity bucket regions; packed entry = src | ldst<<20
__global__ __launch_bounds__(256) void bpart_k(const int* __restrict__ src,
                                               const int* __restrict__ dst,
                                               int* __restrict__ cursor,
                                               int* __restrict__ bucketed, int E, int cap) {
    __shared__ int hist[NBK_MAX];
    __shared__ int base[NBK_MAX];
    for (int i = threadIdx.x; i < NBK_MAX; i += 256) hist[i] = 0;
    __syncthreads();
    int code[PB_MAXI];
#pragma unroll
    for (int i = 0; i < PB_MAXI; i++) {
        code[i] = -1;
        long e = (long)i * (PB_BLOCKS * 256) + (long)blockIdx.x * 256 + threadIdx.x;
        if (e < E) {
            int b = dst[e] >> BK_SHIFT;
            int p = atomicAdd(&hist[b], 1);   // p < 4096 (block edge total)
            code[i] = (b << 12) | p;
        }
    }
    __syncthreads();
    for (int i = threadIdx.x; i < NBK_MAX; i += 256)
        base[i] = hist[i] ? atomicAdd(&cursor[i], hist[i]) : 0;
    __syncthreads();
#pragma unroll
    for (int i = 0; i < PB_MAXI; i++) {
        long e = (long)i * (PB_BLOCKS * 256) + (long)blockIdx.x * 256 + threadIdx.x;
        if (e < E) {
            int b = code[i] >> 12, p = code[i] & 0xFFF;
            int pos = base[b] + p;
            if (pos < (b + 1) * cap)          // overflow guard (never hit for random dst)
                bucketed[pos] = src[e] | ((dst[e] & (BK_NODES - 1)) << 20);
        }
    }
}

// one block per 128-node bucket: counting sort; emits rowbeg/rowend + dinv
__global__ __launch_bounds__(256) void bsort_k(const int* __restrict__ bucketed,
                                               const int* __restrict__ cursor,
                                               int* __restrict__ rowbeg,
                                               int* __restrict__ rowend,
                                               int* __restrict__ sorted_src,
                                               float* __restrict__ dinv, int N, int cap) {
    __shared__ int deg[BK_NODES];
    __shared__ int scn[BK_NODES];
    __shared__ int cur[BK_NODES];
    int b = blockIdx.x, t = threadIdx.x;
    int nstart = b << BK_SHIFT;
    int ncnt = min(BK_NODES, N - nstart);
    int estart = b * cap;
    int ecnt = cursor[b] - estart;            // final cursor = base + count
    if (t < BK_NODES) deg[t] = 0;
    __syncthreads();
    for (int j = t; j < ecnt; j += 256)
        atomicAdd(&deg[bucketed[estart + j] >> 20], 1);
    __syncthreads();
    int myv = (t < BK_NODES) ? deg[t] : 0;
    if (t < BK_NODES) scn[t] = myv;
    __syncthreads();
    for (int off = 1; off < BK_NODES; off <<= 1) {
        int x = (t < BK_NODES && t >= off) ? scn[t - off] : 0;
        __syncthreads();
        if (t < BK_NODES) scn[t] += x;
        __syncthreads();
    }
    if (t < ncnt) {
        int excl = scn[t] - myv;
        rowbeg[nstart + t] = estart + excl;
        rowend[nstart + t] = estart + scn[t];
        dinv[nstart + t] = rsqrtf(1.0f + (float)myv);  // self-loop + in-degree
        cur[t] = excl;
    }
    __syncthreads();
    for (int j = t; j < ecnt; j += 256) {
        int eg = bucketed[estart + j];
        int p = atomicAdd(&cur[eg >> 20], 1);
        sorted_src[estart + p] = eg & 0xFFFFF;
    }
}

// ---------- compute ----------

// hs1[M,64] = ((x[M,128] @ W1) * dinv) in bf16. Thread-per-row, W in LDS.
__global__ __launch_bounds__(256) void gemm1_k(const float* __restrict__ A,
                                               const float* __restrict__ W,
                                               const float* __restrict__ dinv,
                                               __hip_bfloat16* __restrict__ C, int M) {
    __shared__ float lw[INDIM * HID];
    for (int i = threadIdx.x; i < INDIM * HID / 4; i += 256)
        ((float4*)lw)[i] = ((const float4*)W)[i];
    __syncthreads();
    int row = blockIdx.x * 256 + threadIdx.x;
    if (row >= M) return;
    float acc[HID];
#pragma unroll
    for (int c = 0; c < HID; c++) acc[c] = 0.0f;
    const float* a = A + (long)row * INDIM;
    for (int k = 0; k < INDIM; k += 4) {
        float4 v = *(const float4*)(a + k);
        float av[4] = {v.x, v.y, v.z, v.w};
#pragma unroll
        for (int kk = 0; kk < 4; kk++) {
            const float4* wr = (const float4*)(lw + (k + kk) * HID);
#pragma unroll
            for (int c4 = 0; c4 < 16; c4++) {
                float4 w = wr[c4];
                acc[4 * c4 + 0] = fmaf(av[kk], w.x, acc[4 * c4 + 0]);
                acc[4 * c4 + 1] = fmaf(av[kk], w.y, acc[4 * c4 + 1]);
                acc[4 * c4 + 2] = fmaf(av[kk], w.z, acc[4 * c4 + 2]);
                acc[4 * c4 + 3] = fmaf(av[kk], w.w, acc[4 * c4 + 3]);
            }
        }
    }
    float s = dinv[row];
    __hip_bfloat16* out = C + (long)row * HID;
#pragma unroll
    for (int c = 0; c < HID; c += 8) {
        union { uint4 u; __hip_bfloat16 h[8]; } p;
#pragma unroll
        for (int j = 0; j < 8; j++) p.h[j] = __float2bfloat16(acc[c + j] * s);
        *(uint4*)(out + c) = p.u;
    }
}

static __device__ __forceinline__ short f2bf(float f) {
    __hip_bfloat16 h = __float2bfloat16(f);
    return *reinterpret_cast<short*>(&h);
}
static __device__ __forceinline__ float bf2f(short s) {
    return __uint_as_float(((unsigned)(unsigned short)s) << 16);
}

// unpack one dword-pair (4 bf16 features) and accumulate into a0..a3, exact f32 math
#define ACC4(v)                                            \
    do {                                                   \
        a0 += __uint_as_float((v).x << 16);                \
        a1 += __uint_as_float((v).x & 0xffff0000u);        \
        a2 += __uint_as_float((v).y << 16);                \
        a3 += __uint_as_float((v).y & 0xffff0000u);        \
    } while (0)

// fused gather + next-layer GEMM, MFMA epilogue.
// Block = 256 threads = 4 waves handles a 64-node tile.
//  Phase A: stage W (64x64 f32) as hi/lo bf16 MFMA B-fragments in LDS (once per 64
//           nodes, vs per-4-nodes before).
//  Phase B: wave w aggregates its 16 nodes in 16 rounds (16 lanes x 4 edge-streams,
//           uint2 bf16-quad gather, shfl_xor merge — unchanged inner loop). The relu'd
//           aggregate r is split r = rh + rl (bf16 hi/lo; dropped rl*wl term ~2^-15,
//           so FC precision >= the old f32 VALU FC) and written to an LDS A-tile with
//           the T2 XOR swizzle (16B block ^= row&7) to avoid the stride-128B conflict.
//  Phase C: FC via 24 mfma_f32_16x16x32_bf16 per wave (3 hi/lo terms x 2 kt x 4 nt)
//           ~5 issue slots/node vs ~192 for the readlane FC.
// C/D layout (m89-verified): col = lane&15, row = (lane>>4)*4 + reg.
template <bool HS_OUT>
__global__ __launch_bounds__(256) void fgather_k(void* __restrict__ outp,
                                                 const __hip_bfloat16* __restrict__ hs,
                                                 const float* __restrict__ dinv,
                                                 const float* __restrict__ biasA,
                                                 const float* __restrict__ Wn,
                                                 const float* __restrict__ biasB,
                                                 const int* __restrict__ rowbeg,
                                                 const int* __restrict__ rowend,
                                                 const int* __restrict__ sorted_src, int n) {
    __shared__ __align__(16) short WH[512 * 8];   // B-frags hi: [(kt*4+nt)*64 + lane][8]
    __shared__ __align__(16) short WL[512 * 8];   // B-frags lo
    __shared__ __align__(16) short RH[64 * 64];   // A-tile hi: [row][8 x 16B-block ^ row&7]
    __shared__ __align__(16) short RL[64 * 64];   // A-tile lo

    int t = threadIdx.x;
    int lane = t & 63;
    int wid = __builtin_amdgcn_readfirstlane(t >> 6);
    int q = lane & 15, g = lane >> 4;
    int tile = blockIdx.x << 6;

    // ---- Phase A: stage W fragments (hi/lo bf16) ----
    // slot sid = (kt*4+nt)*64 + fraglane; fraglane holds B[k...k+7][col] contiguous.
#pragma unroll
    for (int s = 0; s < 2; s++) {
        int sid = t + s * 256;
        int col = (((sid >> 6) & 3) << 4) + (sid & 15);
        int kb = ((sid >> 8) << 5) + (((sid >> 4) & 3) << 3);
        union { short s[8]; uint4 u; } ph, pl;
#pragma unroll
        for (int i = 0; i < 8; i++) {
            float w = Wn[(kb + i) * 64 + col];
            short h = f2bf(w);
            ph.s[i] = h;
            pl.s[i] = f2bf(w - bf2f(h));
        }
        *((uint4*)WH + sid) = ph.u;
        *((uint4*)WL + sid) = pl.u;
    }
    float4 bb = *(const float4*)(biasA + (q << 2));
    __syncthreads();

    // ---- Phase B: aggregation rounds (wave-per-node) ----
    int fo = q << 2;                          // feature quad offset
    for (int r = 0; r < 16; r++) {
        int nd = tile + (wid << 4) + r;
        if (nd >= n) break;                   // wave-uniform
        int e0 = __builtin_amdgcn_readfirstlane(rowbeg[nd]);
        int e1 = __builtin_amdgcn_readfirstlane(rowend[nd]);
        float a0 = 0.f, a1 = 0.f, a2 = 0.f, a3 = 0.f;
        int e = e0;
        for (; e + 16 <= e1; e += 16) {
            int i0 = sorted_src[e + g];
            int i1 = sorted_src[e + 4 + g];
            int i2 = sorted_src[e + 8 + g];
            int i3 = sorted_src[e + 12 + g];
            uint2 v0 = *(const uint2*)(hs + ((i0 << 6) + fo));
            uint2 v1 = *(const uint2*)(hs + ((i1 << 6) + fo));
            uint2 v2 = *(const uint2*)(hs + ((i2 << 6) + fo));
            uint2 v3 = *(const uint2*)(hs + ((i3 << 6) + fo));
            ACC4(v0); ACC4(v1); ACC4(v2); ACC4(v3);
        }
        if (e < e1) {                         // one clamped 16-edge tail block
            int last = e1 - 1;
            int m0 = e + g, m1 = m0 + 4, m2 = m0 + 8, m3 = m0 + 12;
            int i0 = sorted_src[m0 <= last ? m0 : last];
            int i1 = sorted_src[m1 <= last ? m1 : last];
            int i2 = sorted_src[m2 <= last ? m2 : last];
            int i3 = sorted_src[m3 <= last ? m3 : last];
            uint2 v0 = *(const uint2*)(hs + ((i0 << 6) + fo));
            uint2 v1 = *(const uint2*)(hs + ((i1 << 6) + fo));
            uint2 v2 = *(const uint2*)(hs + ((i2 << 6) + fo));
            uint2 v3 = *(const uint2*)(hs + ((i3 << 6) + fo));
            if (m0 > last) { v0.x = 0u; v0.y = 0u; }
            if (m1 > last) { v1.x = 0u; v1.y = 0u; }
            if (m2 > last) { v2.x = 0u; v2.y = 0u; }
            if (m3 > last) { v3.x = 0u; v3.y = 0u; }
            ACC4(v0); ACC4(v1); ACC4(v2); ACC4(v3);
        }
        // merge the 4 edge sub-streams
        a0 += __shfl_xor(a0, 16); a1 += __shfl_xor(a1, 16);
        a2 += __shfl_xor(a2, 16); a3 += __shfl_xor(a3, 16);
        a0 += __shfl_xor(a0, 32); a1 += __shfl_xor(a1, 32);
        a2 += __shfl_xor(a2, 32); a3 += __shfl_xor(a3, 32);
        // self-loop term
        uint2 sv = *(const uint2*)(hs + ((nd << 6) + fo));
        ACC4(sv);
        float di = dinv[nd];
        float r0 = fmaxf(fmaf(di, a0, bb.x), 0.0f);
        float r1 = fmaxf(fmaf(di, a1, bb.y), 0.0f);
        float r2 = fmaxf(fmaf(di, a2, bb.z), 0.0f);
        float r3 = fmaxf(fmaf(di, a3, bb.w), 0.0f);
        if (lane < 16) {                      // lanes 0-15 hold the merged quads
            union { short s[4]; uint2 u; } ph, pl;
            ph.s[0] = f2bf(r0); pl.s[0] = f2bf(r0 - bf2f(ph.s[0]));
            ph.s[1] = f2bf(r1); pl.s[1] = f2bf(r1 - bf2f(ph.s[1]));
            ph.s[2] = f2bf(r2); pl.s[2] = f2bf(r2 - bf2f(ph.s[2]));
            ph.s[3] = f2bf(r3); pl.s[3] = f2bf(r3 - bf2f(ph.s[3]));
            int rowloc = (wid << 4) + r;
            int boff = rowloc * 128 + ((((q >> 1) ^ (rowloc & 7)) << 4)) + ((q & 1) << 3);
            *(uint2*)((char*)RH + boff) = ph.u;
            *(uint2*)((char*)RL + boff) = pl.u;
        }
    }
    __syncthreads();

    // ---- Phase C: FC via MFMA ----
    f32x4 acc[4] = {};
#pragma unroll
    for (int kt = 0; kt < 2; kt++) {
        int arow = (wid << 4) + q;            // arow&7 == q&7 == write-side rowloc&7
        int aoff = arow * 128 + ((((kt << 2) + g) ^ (q & 7)) << 4);
        bf16x8 ah = *(const bf16x8*)((const char*)RH + aoff);
        bf16x8 al = *(const bf16x8*)((const char*)RL + aoff);
#pragma unroll
        for (int nt = 0; nt < 4; nt++) {
            int soff = (((((kt << 2) + nt) << 6) + lane)) << 4;
            bf16x8 bh = *(const bf16x8*)((const char*)WH + soff);
            bf16x8 bl = *(const bf16x8*)((const char*)WL + soff);
            acc[nt] = __builtin_amdgcn_mfma_f32_16x16x32_bf16(ah, bh, acc[nt], 0, 0, 0);
            acc[nt] = __builtin_amdgcn_mfma_f32_16x16x32_bf16(ah, bl, acc[nt], 0, 0, 0);
            acc[nt] = __builtin_amdgcn_mfma_f32_16x16x32_bf16(al, bh, acc[nt], 0, 0, 0);
        }
    }

    // ---- epilogue: C[row = (g<<2)+reg][col = (nt<<4)+q] ----
    int rbase = tile + (wid << 4);
    if (HS_OUT) {
        __hip_bfloat16* out = (__hip_bfloat16*)outp;
#pragma unroll
        for (int reg = 0; reg < 4; reg++) {
            int node = rbase + (g << 2) + reg;
            if (node < n) {
                float di = dinv[node];
#pragma unroll
                for (int nt = 0; nt < 4; nt++)
                    out[(node << 6) + (nt << 4) + q] = __float2bfloat16(acc[nt][reg] * di);
            }
        }
    } else {
        float* out = (float*)outp;
        float bB[4];
#pragma unroll
        for (int nt = 0; nt < 4; nt++) bB[nt] = biasB[(nt << 4) + q];
#pragma unroll
        for (int reg = 0; reg < 4; reg++) {
            int node = rbase + (g << 2) + reg;
            if (node < n) {
#pragma unroll
                for (int nt = 0; nt < 4; nt++)
                    out[(node << 6) + (nt << 4) + q] = acc[nt][reg] + bB[nt];
            }
        }
    }
}

extern "C" void kernel_launch(void* const* d_in, const int* in_sizes, int n_in,
                              void* d_out, int out_size, void* d_ws, size_t ws_size,
                              hipStream_t stream) {
    const float* x   = (const float*)d_in[0];
    const int*   ei  = (const int*)d_in[1];
    const float* W1  = (const float*)d_in[2];
    const float* b1  = (const float*)d_in[3];
    const float* W2  = (const float*)d_in[4];
    const float* b2  = (const float*)d_in[5];
    const float* Wfc = (const float*)d_in[6];
    const float* bfc = (const float*)d_in[7];

    int N = in_sizes[0] / INDIM;
    int E = in_sizes[1] / 2;
    const int* src = ei;       // edge_index row 0
    const int* dst = ei + E;   // edge_index row 1
    int nb = (N + BK_NODES - 1) >> BK_SHIFT;          // 782 buckets
    int cap = (2 * E / nb + 63) & ~63;                // 2x mean bucket load
    if (cap < 4096) cap = 4096;

    char* ws = (char*)d_ws;
    auto alloc = [&](size_t bytes) {
        char* p = ws;
        ws += (bytes + 15) & ~(size_t)15;
        return p;
    };
    int*   rowbeg     = (int*)alloc(sizeof(int) * (size_t)N);
    int*   rowend     = (int*)alloc(sizeof(int) * (size_t)N);
    float* dinv       = (float*)alloc(sizeof(float) * (size_t)N);
    int*   cursor     = (int*)alloc(sizeof(int) * NBK_MAX);
    int*   sorted_src = (int*)alloc(sizeof(int) * (size_t)nb * cap);
    // big region: bucketed (int, nb*cap) first; later hs1+hs2 (bf16, 2*N*64).
    size_t big_bytes = sizeof(int) * (size_t)nb * cap;
    size_t hs_bytes  = sizeof(__hip_bfloat16) * 2 * (size_t)N * HID;
    char*  big       = alloc(big_bytes > hs_bytes ? big_bytes : hs_bytes);
    int*   bucketed  = (int*)big;
    __hip_bfloat16* hs1 = (__hip_bfloat16*)big;
    __hip_bfloat16* hs2 = hs1 + (size_t)N * HID;
    float* outp      = (float*)d_out;

    // build: 3 dispatches
    cinit_k<<<(nb + 255) / 256, 256, 0, stream>>>(cursor, nb, cap);
    bpart_k<<<PB_BLOCKS, 256, 0, stream>>>(src, dst, cursor, bucketed, E, cap);
    bsort_k<<<nb, 256, 0, stream>>>(bucketed, cursor, rowbeg, rowend, sorted_src, dinv, N, cap);

    // compute: 3 dispatches
    gemm1_k<<<(N + 255) / 256, 256, 0, stream>>>(x, W1, dinv, hs1, N);
    fgather_k<true><<<(N + 63) / 64, 256, 0, stream>>>(hs2, hs1, dinv, b1, W2, nullptr,
                                                       rowbeg, rowend, sorted_src, N);
    fgather_k<false><<<(N + 63) / 64, 256, 0, stream>>>(outp, hs2, dinv, b2, Wfc, bfc,
                                                        rowbeg, rowend, sorted_src, N);
}

// Round 3
// 272.981 us; speedup vs baseline: 1.3185x; 1.1223x over previous
//
#include <hip/hip_runtime.h>
#include <hip/hip_bf16.h>

#define HID 64
#define INDIM 128
#define BK_SHIFT 7            // 128 nodes per bucket
#define BK_NODES 128
#define NBK_MAX 1024          // supports N <= 131072
#define PB_BLOCKS 512
#define PB_MAXI 16            // supports E <= 512*256*16 = 2.097M

typedef __attribute__((ext_vector_type(8))) short bf16x8;
typedef __attribute__((ext_vector_type(4))) float f32x4;

// 16B load from a 4B-aligned address (sorted_src + arbitrary e)
struct __attribute__((packed, aligned(4))) u4u { unsigned x, y, z, w; };

// ---------- CSR build: fixed-capacity buckets ----------
// cursor[] is zero-initialized by hipMemsetAsync; bucket base offset b*cap is added
// at claim time (cinit_k removed).

__global__ __launch_bounds__(256) void bpart_k(const int* __restrict__ src,
                                               const int* __restrict__ dst,
                                               int* __restrict__ cursor,
                                               int* __restrict__ bucketed, int E, int cap) {
    __shared__ int hist[NBK_MAX];
    __shared__ int base[NBK_MAX];
    for (int i = threadIdx.x; i < NBK_MAX; i += 256) hist[i] = 0;
    __syncthreads();
    int code[PB_MAXI];
#pragma unroll
    for (int i = 0; i < PB_MAXI; i++) {
        code[i] = -1;
        long e = (long)i * (PB_BLOCKS * 256) + (long)blockIdx.x * 256 + threadIdx.x;
        if (e < E) {
            int b = dst[e] >> BK_SHIFT;
            int p = atomicAdd(&hist[b], 1);   // p < 4096 (block edge total)
            code[i] = (b << 12) | p;
        }
    }
    __syncthreads();
    for (int i = threadIdx.x; i < NBK_MAX; i += 256)
        base[i] = hist[i] ? (i * cap + atomicAdd(&cursor[i], hist[i])) : 0;
    __syncthreads();
#pragma unroll
    for (int i = 0; i < PB_MAXI; i++) {
        long e = (long)i * (PB_BLOCKS * 256) + (long)blockIdx.x * 256 + threadIdx.x;
        if (e < E) {
            int b = code[i] >> 12, p = code[i] & 0xFFF;
            int pos = base[b] + p;
            if (pos < (b + 1) * cap)          // overflow guard (never hit for random dst)
                bucketed[pos] = src[e] | ((dst[e] & (BK_NODES - 1)) << 20);
        }
    }
}

// one block per 128-node bucket: counting sort; emits rowbeg/rowend + dinv
__global__ __launch_bounds__(256) void bsort_k(const int* __restrict__ bucketed,
                                               const int* __restrict__ cursor,
                                               int* __restrict__ rowbeg,
                                               int* __restrict__ rowend,
                                               int* __restrict__ sorted_src,
                                               float* __restrict__ dinv, int N, int cap) {
    __shared__ int deg[BK_NODES];
    __shared__ int scn[BK_NODES];
    __shared__ int cur[BK_NODES];
    int b = blockIdx.x, t = threadIdx.x;
    int nstart = b << BK_SHIFT;
    int ncnt = min(BK_NODES, N - nstart);
    int estart = b * cap;
    int ecnt = cursor[b];                     // count (cursor started at 0)
    if (t < BK_NODES) deg[t] = 0;
    __syncthreads();
    for (int j = t; j < ecnt; j += 256)
        atomicAdd(&deg[bucketed[estart + j] >> 20], 1);
    __syncthreads();
    int myv = (t < BK_NODES) ? deg[t] : 0;
    if (t < BK_NODES) scn[t] = myv;
    __syncthreads();
    for (int off = 1; off < BK_NODES; off <<= 1) {
        int x = (t < BK_NODES && t >= off) ? scn[t - off] : 0;
        __syncthreads();
        if (t < BK_NODES) scn[t] += x;
        __syncthreads();
    }
    if (t < ncnt) {
        int excl = scn[t] - myv;
        rowbeg[nstart + t] = estart + excl;
        rowend[nstart + t] = estart + scn[t];
        dinv[nstart + t] = rsqrtf(1.0f + (float)myv);  // self-loop + in-degree
        cur[t] = excl;
    }
    __syncthreads();
    for (int j = t; j < ecnt; j += 256) {
        int eg = bucketed[estart + j];
        int p = atomicAdd(&cur[eg >> 20], 1);
        sorted_src[estart + p] = eg & 0xFFFFF;
    }
}

// ---------- compute ----------

// hs1[M,64] = ((x[M,128] @ W1) * dinv) in bf16. Thread-per-row, W in LDS.
__global__ __launch_bounds__(256) void gemm1_k(const float* __restrict__ A,
                                               const float* __restrict__ W,
                                               const float* __restrict__ dinv,
                                               __hip_bfloat16* __restrict__ C, int M) {
    __shared__ float lw[INDIM * HID];
    for (int i = threadIdx.x; i < INDIM * HID / 4; i += 256)
        ((float4*)lw)[i] = ((const float4*)W)[i];
    __syncthreads();
    int row = blockIdx.x * 256 + threadIdx.x;
    if (row >= M) return;
    float acc[HID];
#pragma unroll
    for (int c = 0; c < HID; c++) acc[c] = 0.0f;
    const float* a = A + (long)row * INDIM;
    for (int k = 0; k < INDIM; k += 4) {
        float4 v = *(const float4*)(a + k);
        float av[4] = {v.x, v.y, v.z, v.w};
#pragma unroll
        for (int kk = 0; kk < 4; kk++) {
            const float4* wr = (const float4*)(lw + (k + kk) * HID);
#pragma unroll
            for (int c4 = 0; c4 < 16; c4++) {
                float4 w = wr[c4];
                acc[4 * c4 + 0] = fmaf(av[kk], w.x, acc[4 * c4 + 0]);
                acc[4 * c4 + 1] = fmaf(av[kk], w.y, acc[4 * c4 + 1]);
                acc[4 * c4 + 2] = fmaf(av[kk], w.z, acc[4 * c4 + 2]);
                acc[4 * c4 + 3] = fmaf(av[kk], w.w, acc[4 * c4 + 3]);
            }
        }
    }
    float s = dinv[row];
    __hip_bfloat16* out = C + (long)row * HID;
#pragma unroll
    for (int c = 0; c < HID; c += 8) {
        union { uint4 u; __hip_bfloat16 h[8]; } p;
#pragma unroll
        for (int j = 0; j < 8; j++) p.h[j] = __float2bfloat16(acc[c + j] * s);
        *(uint4*)(out + c) = p.u;
    }
}

static __device__ __forceinline__ short f2bf(float f) {
    __hip_bfloat16 h = __float2bfloat16(f);
    return *reinterpret_cast<short*>(&h);
}
static __device__ __forceinline__ float bf2f(short s) {
    return __uint_as_float(((unsigned)(unsigned short)s) << 16);
}

#define LO16(u) __uint_as_float((u) << 16)
#define HI16(u) __uint_as_float((u) & 0xffff0000u)
// unpack one dwordx4 (8 bf16 features) into a[0..7], exact f32 math
#define ACC8(v)                                            \
    do {                                                   \
        a[0] += LO16((v).x); a[1] += HI16((v).x);          \
        a[2] += LO16((v).y); a[3] += HI16((v).y);          \
        a[4] += LO16((v).z); a[5] += HI16((v).z);          \
        a[6] += LO16((v).w); a[7] += HI16((v).w);          \
    } while (0)

// fused gather + next-layer GEMM, MFMA epilogue. Block = 4 waves = 64-node tile.
//  Phase A: stage W (64x64 f32) as hi/lo bf16 MFMA B-fragments in LDS.
//  Phase B: each wave aggregates TWO nodes per round (8 rounds for its 16 rows):
//           32 lanes/node = 8 feature-lanes (uint4 = 8 bf16) x 4 edge-streams.
//           Idx loads are one dwordx4 per stream (4 consecutive edges). rowbeg/rowend
//           preloaded for all 16 rows, distributed by __shfl. Tail = one clamped
//           16-edge block per node; clamped lanes redirect to the zeroed row hs[n].
//           Result split r = rh + rl (bf16 hi/lo) into the swizzled LDS A-tile
//           (16B block f ^ row&7). RH/RL rows are wave-private -> NO barrier between
//           B and C; the single barrier covers A-staging -> C.
//  Phase C: 24 mfma_f32_16x16x32_bf16 per wave (3 hi/lo terms x 2 kt x 4 nt).
// C/D layout (m89-verified): col = lane&15, row = (lane>>4)*4 + reg.
template <bool HS_OUT>
__global__ __launch_bounds__(256) void fgather_k(void* __restrict__ outp,
                                                 const __hip_bfloat16* __restrict__ hs,
                                                 const float* __restrict__ dinv,
                                                 const float* __restrict__ biasA,
                                                 const float* __restrict__ Wn,
                                                 const float* __restrict__ biasB,
                                                 const int* __restrict__ rowbeg,
                                                 const int* __restrict__ rowend,
                                                 const int* __restrict__ sorted_src, int n) {
    __shared__ __align__(16) short WH[512 * 8];   // B-frags hi: [(kt*4+nt)*64 + lane][8]
    __shared__ __align__(16) short WL[512 * 8];   // B-frags lo
    __shared__ __align__(16) short RH[64 * 64];   // A-tile hi: [row][8 x 16B-block ^ row&7]
    __shared__ __align__(16) short RL[64 * 64];   // A-tile lo

    int t = threadIdx.x;
    int lane = t & 63;
    int wid = __builtin_amdgcn_readfirstlane(t >> 6);
    int q = lane & 15, g = lane >> 4;             // phase A/C coords
    int tile = blockIdx.x << 6;

    // ---- Phase A: stage W fragments (hi/lo bf16) ----
#pragma unroll
    for (int s = 0; s < 2; s++) {
        int sid = t + s * 256;
        int col = (((sid >> 6) & 3) << 4) + (sid & 15);
        int kb = ((sid >> 8) << 5) + (((sid >> 4) & 3) << 3);
        union { short s[8]; uint4 u; } ph, pl;
#pragma unroll
        for (int i = 0; i < 8; i++) {
            float w = Wn[(kb + i) * 64 + col];
            short h = f2bf(w);
            ph.s[i] = h;
            pl.s[i] = f2bf(w - bf2f(h));
        }
        *((uint4*)WH + sid) = ph.u;
        *((uint4*)WL + sid) = pl.u;
    }

    // ---- Phase B: aggregation, 2 nodes per wave-round ----
    int half = lane >> 5;                     // which node of the pair
    int g2 = (lane >> 3) & 3;                 // edge sub-stream 0..3
    int f8 = lane & 7;                        // feature octet 0..7
    int fo8 = f8 << 3;
    int rbv = 0, rev = 0;
    {
        int ndl = tile + (wid << 4) + (lane & 15);
        if (lane < 16 && ndl < n) { rbv = rowbeg[ndl]; rev = rowend[ndl]; }
    }
    __align__(16) float bb8[8];
    *(float4*)(bb8)     = *(const float4*)(biasA + fo8);
    *(float4*)(bb8 + 4) = *(const float4*)(biasA + fo8 + 4);

    for (int r = 0; r < 8; r++) {
        int row = (wid << 4) + (r << 1) + half;
        int nd = tile + row;
        int e0 = __shfl(rbv, row & 15);
        int e1 = __shfl(rev, row & 15);
        float a[8] = {0.f, 0.f, 0.f, 0.f, 0.f, 0.f, 0.f, 0.f};
        int e = e0;
        for (; e + 16 <= e1; e += 16) {       // 16 edges per node per iter
            u4u iv = *(const u4u*)(sorted_src + e + (g2 << 2));
            uint4 v0 = *(const uint4*)(hs + (((int)iv.x << 6) + fo8));
            uint4 v1 = *(const uint4*)(hs + (((int)iv.y << 6) + fo8));
            uint4 v2 = *(const uint4*)(hs + (((int)iv.z << 6) + fo8));
            uint4 v3 = *(const uint4*)(hs + (((int)iv.w << 6) + fo8));
            ACC8(v0); ACC8(v1); ACC8(v2); ACC8(v3);
        }
        if (e < e1) {                         // one clamped 16-edge tail block
            int last = e1 - 1;
            int m0 = e + (g2 << 2), m1 = m0 + 1, m2 = m0 + 2, m3 = m0 + 3;
            int i0 = sorted_src[m0 <= last ? m0 : last]; if (m0 > last) i0 = n;
            int i1 = sorted_src[m1 <= last ? m1 : last]; if (m1 > last) i1 = n;
            int i2 = sorted_src[m2 <= last ? m2 : last]; if (m2 > last) i2 = n;
            int i3 = sorted_src[m3 <= last ? m3 : last]; if (m3 > last) i3 = n;
            uint4 v0 = *(const uint4*)(hs + ((i0 << 6) + fo8));
            uint4 v1 = *(const uint4*)(hs + ((i1 << 6) + fo8));
            uint4 v2 = *(const uint4*)(hs + ((i2 << 6) + fo8));
            uint4 v3 = *(const uint4*)(hs + ((i3 << 6) + fo8));
            ACC8(v0); ACC8(v1); ACC8(v2); ACC8(v3);
        }
        // merge the 4 edge sub-streams (within each 32-lane half)
#pragma unroll
        for (int k = 0; k < 8; k++) a[k] += __shfl_xor(a[k], 8);
#pragma unroll
        for (int k = 0; k < 8; k++) a[k] += __shfl_xor(a[k], 16);
        // self-loop term (zero row for OOB)
        int snd = nd < n ? nd : n;
        uint4 sv = *(const uint4*)(hs + ((snd << 6) + fo8));
        ACC8(sv);
        float di = dinv[nd < n ? nd : 0];
        union { short s[8]; uint4 u; } ph, pl;
#pragma unroll
        for (int k = 0; k < 8; k++) {
            float rk = fmaxf(fmaf(di, a[k], bb8[k]), 0.f);
            short h = f2bf(rk);
            ph.s[k] = h;
            pl.s[k] = f2bf(rk - bf2f(h));
        }
        if (g2 == 0 && nd < n) {              // 8 lanes per half write the row
            int boff = row * 128 + ((f8 ^ (row & 7)) << 4);
            *(uint4*)((char*)RH + boff) = ph.u;
            *(uint4*)((char*)RL + boff) = pl.u;
        }
    }
    __syncthreads();                          // A-staging (and all RH/RL) -> Phase C

    // ---- Phase C: FC via MFMA ----
    f32x4 acc[4] = {};
#pragma unroll
    for (int kt = 0; kt < 2; kt++) {
        int arow = (wid << 4) + q;            // arow&7 == q&7 == write-side row&7
        int aoff = arow * 128 + ((((kt << 2) + g) ^ (q & 7)) << 4);
        bf16x8 ah = *(const bf16x8*)((const char*)RH + aoff);
        bf16x8 al = *(const bf16x8*)((const char*)RL + aoff);
#pragma unroll
        for (int nt = 0; nt < 4; nt++) {
            int soff = (((((kt << 2) + nt) << 6) + lane)) << 4;
            bf16x8 bh = *(const bf16x8*)((const char*)WH + soff);
            bf16x8 bl = *(const bf16x8*)((const char*)WL + soff);
            acc[nt] = __builtin_amdgcn_mfma_f32_16x16x32_bf16(ah, bh, acc[nt], 0, 0, 0);
            acc[nt] = __builtin_amdgcn_mfma_f32_16x16x32_bf16(ah, bl, acc[nt], 0, 0, 0);
            acc[nt] = __builtin_amdgcn_mfma_f32_16x16x32_bf16(al, bh, acc[nt], 0, 0, 0);
        }
    }

    // ---- epilogue: C[row = (g<<2)+reg][col = (nt<<4)+q] ----
    int rbase = tile + (wid << 4);
    if (HS_OUT) {
        __hip_bfloat16* out = (__hip_bfloat16*)outp;
#pragma unroll
        for (int reg = 0; reg < 4; reg++) {
            int node = rbase + (g << 2) + reg;
            if (node < n) {
                float di = dinv[node];
#pragma unroll
                for (int nt = 0; nt < 4; nt++)
                    out[(node << 6) + (nt << 4) + q] = __float2bfloat16(acc[nt][reg] * di);
            }
        }
    } else {
        float* out = (float*)outp;
        float bB[4];
#pragma unroll
        for (int nt = 0; nt < 4; nt++) bB[nt] = biasB[(nt << 4) + q];
#pragma unroll
        for (int reg = 0; reg < 4; reg++) {
            int node = rbase + (g << 2) + reg;
            if (node < n) {
#pragma unroll
                for (int nt = 0; nt < 4; nt++)
                    out[(node << 6) + (nt << 4) + q] = acc[nt][reg] + bB[nt];
            }
        }
    }
}

extern "C" void kernel_launch(void* const* d_in, const int* in_sizes, int n_in,
                              void* d_out, int out_size, void* d_ws, size_t ws_size,
                              hipStream_t stream) {
    const float* x   = (const float*)d_in[0];
    const int*   ei  = (const int*)d_in[1];
    const float* W1  = (const float*)d_in[2];
    const float* b1  = (const float*)d_in[3];
    const float* W2  = (const float*)d_in[4];
    const float* b2  = (const float*)d_in[5];
    const float* Wfc = (const float*)d_in[6];
    const float* bfc = (const float*)d_in[7];

    int N = in_sizes[0] / INDIM;
    int E = in_sizes[1] / 2;
    const int* src = ei;       // edge_index row 0
    const int* dst = ei + E;   // edge_index row 1
    int nb = (N + BK_NODES - 1) >> BK_SHIFT;          // 782 buckets
    int cap = (2 * E / nb + 63) & ~63;                // 2x mean bucket load
    if (cap < 4096) cap = 4096;

    char* ws = (char*)d_ws;
    auto alloc = [&](size_t bytes) {
        char* p = ws;
        ws += (bytes + 15) & ~(size_t)15;
        return p;
    };
    int*   rowbeg     = (int*)alloc(sizeof(int) * (size_t)N);
    int*   rowend     = (int*)alloc(sizeof(int) * (size_t)N);
    float* dinv       = (float*)alloc(sizeof(float) * (size_t)N);
    int*   cursor     = (int*)alloc(sizeof(int) * NBK_MAX);
    int*   sorted_src = (int*)alloc(sizeof(int) * (size_t)nb * cap);
    // big region: bucketed (int, nb*cap) first; later hs1+hs2 (bf16, 2*(N+1)*64,
    // each with a zeroed guard row at index N for clamped tail/OOB lanes).
    size_t big_bytes = sizeof(int) * (size_t)nb * cap;
    size_t hs_bytes  = sizeof(__hip_bfloat16) * 2 * (size_t)(N + 1) * HID;
    char*  big       = alloc(big_bytes > hs_bytes ? big_bytes : hs_bytes);
    int*   bucketed  = (int*)big;
    __hip_bfloat16* hs1 = (__hip_bfloat16*)big;
    __hip_bfloat16* hs2 = hs1 + (size_t)(N + 1) * HID;
    float* outp      = (float*)d_out;

    // build: memset + 2 dispatches
    hipMemsetAsync(cursor, 0, NBK_MAX * sizeof(int), stream);
    bpart_k<<<PB_BLOCKS, 256, 0, stream>>>(src, dst, cursor, bucketed, E, cap);
    bsort_k<<<nb, 256, 0, stream>>>(bucketed, cursor, rowbeg, rowend, sorted_src, dinv, N, cap);

    // zero guard rows (after bucketed is consumed; big region is reused as hs1/hs2)
    hipMemsetAsync(hs1 + (size_t)N * HID, 0, HID * sizeof(__hip_bfloat16), stream);
    hipMemsetAsync(hs2 + (size_t)N * HID, 0, HID * sizeof(__hip_bfloat16), stream);

    // compute: 3 dispatches
    gemm1_k<<<(N + 255) / 256, 256, 0, stream>>>(x, W1, dinv, hs1, N);
    fgather_k<true><<<(N + 63) / 64, 256, 0, stream>>>(hs2, hs1, dinv, b1, W2, nullptr,
                                                       rowbeg, rowend, sorted_src, N);
    fgather_k<false><<<(N + 63) / 64, 256, 0, stream>>>(outp, hs2, dinv, b2, Wfc, bfc,
                                                        rowbeg, rowend, sorted_src, N);
}

// Round 4
// 241.983 us; speedup vs baseline: 1.4875x; 1.1281x over previous
//
#include <hip/hip_runtime.h>
#include <hip/hip_bf16.h>

#define HID 64
#define INDIM 128
#define BK_SHIFT 7            // 128 nodes per bucket
#define BK_NODES 128
#define NBK_MAX 1024          // supports N <= 131072
#define PB_BLOCKS 512
#define PB_MAXI 16            // supports E <= 512*256*16 = 2.097M

typedef __attribute__((ext_vector_type(8))) short bf16x8;
typedef __attribute__((ext_vector_type(4))) float f32x4;

// 16B load from a 4B-aligned address (sorted_src + arbitrary e)
struct __attribute__((packed, aligned(4))) u4u { unsigned x, y, z, w; };

// ---------- CSR build: fixed-capacity buckets ----------
// cursor[] is zero-initialized by hipMemsetAsync; bucket base offset b*cap is added
// at claim time.

__global__ __launch_bounds__(256) void bpart_k(const int* __restrict__ src,
                                               const int* __restrict__ dst,
                                               int* __restrict__ cursor,
                                               int* __restrict__ bucketed, int E, int cap) {
    __shared__ int hist[NBK_MAX];
    __shared__ int base[NBK_MAX];
    for (int i = threadIdx.x; i < NBK_MAX; i += 256) hist[i] = 0;
    __syncthreads();
    int code[PB_MAXI];
#pragma unroll
    for (int i = 0; i < PB_MAXI; i++) {
        code[i] = -1;
        long e = (long)i * (PB_BLOCKS * 256) + (long)blockIdx.x * 256 + threadIdx.x;
        if (e < E) {
            int b = dst[e] >> BK_SHIFT;
            int p = atomicAdd(&hist[b], 1);   // p < 4096 (block edge total)
            code[i] = (b << 12) | p;
        }
    }
    __syncthreads();
    for (int i = threadIdx.x; i < NBK_MAX; i += 256)
        base[i] = hist[i] ? (i * cap + atomicAdd(&cursor[i], hist[i])) : 0;
    __syncthreads();
#pragma unroll
    for (int i = 0; i < PB_MAXI; i++) {
        long e = (long)i * (PB_BLOCKS * 256) + (long)blockIdx.x * 256 + threadIdx.x;
        if (e < E) {
            int b = code[i] >> 12, p = code[i] & 0xFFF;
            int pos = base[b] + p;
            if (pos < (b + 1) * cap)          // overflow guard (never hit for random dst)
                bucketed[pos] = src[e] | ((dst[e] & (BK_NODES - 1)) << 20);
        }
    }
}

// one block per 128-node bucket: counting sort; emits rowbeg/rowend + dinv
__global__ __launch_bounds__(256) void bsort_k(const int* __restrict__ bucketed,
                                               const int* __restrict__ cursor,
                                               int* __restrict__ rowbeg,
                                               int* __restrict__ rowend,
                                               int* __restrict__ sorted_src,
                                               float* __restrict__ dinv, int N, int cap) {
    __shared__ int deg[BK_NODES];
    __shared__ int scn[BK_NODES];
    __shared__ int cur[BK_NODES];
    int b = blockIdx.x, t = threadIdx.x;
    int nstart = b << BK_SHIFT;
    int ncnt = min(BK_NODES, N - nstart);
    int estart = b * cap;
    int ecnt = cursor[b];                     // count (cursor started at 0)
    if (t < BK_NODES) deg[t] = 0;
    __syncthreads();
    for (int j = t; j < ecnt; j += 256)
        atomicAdd(&deg[bucketed[estart + j] >> 20], 1);
    __syncthreads();
    int myv = (t < BK_NODES) ? deg[t] : 0;
    if (t < BK_NODES) scn[t] = myv;
    __syncthreads();
    for (int off = 1; off < BK_NODES; off <<= 1) {
        int x = (t < BK_NODES && t >= off) ? scn[t - off] : 0;
        __syncthreads();
        if (t < BK_NODES) scn[t] += x;
        __syncthreads();
    }
    if (t < ncnt) {
        int excl = scn[t] - myv;
        rowbeg[nstart + t] = estart + excl;
        rowend[nstart + t] = estart + scn[t];
        dinv[nstart + t] = rsqrtf(1.0f + (float)myv);  // self-loop + in-degree
        cur[t] = excl;
    }
    __syncthreads();
    for (int j = t; j < ecnt; j += 256) {
        int eg = bucketed[estart + j];
        int p = atomicAdd(&cur[eg >> 20], 1);
        sorted_src[estart + p] = eg & 0xFFFFF;
    }
}

// ---------- compute ----------

static __device__ __forceinline__ short f2bf(float f) {
    __hip_bfloat16 h = __float2bfloat16(f);
    return *reinterpret_cast<short*>(&h);
}
static __device__ __forceinline__ float bf2f(short s) {
    return __uint_as_float(((unsigned)(unsigned short)s) << 16);
}

// hs1[M,64] = ((x[M,128] @ W1) * dinv) in bf16, via MFMA with hi/lo bf16 split.
// x = xh + xl, W = wh + wl; acc = xh*wh + xh*wl + xl*wh (dropped xl*wl ~2^-26 rel).
// A-frag layout (HW-verified by fgather Phase C): row = lane&15, k = (lane>>4)*8+i
// -> A-frags load DIRECTLY from global x (8 consecutive f32 per lane per k-tile).
// B-frags (W1, 128x64) staged once per block in LDS, same slot scheme as fgather.
// Block = 4 waves = 64 rows; wave = 16 rows x 64 cols; 4 k-tiles x 4 nt x 3 = 48 MFMA.
__global__ __launch_bounds__(256) void gemm1_k(const float* __restrict__ A,
                                               const float* __restrict__ W,
                                               const float* __restrict__ dinv,
                                               __hip_bfloat16* __restrict__ C, int M) {
    __shared__ __align__(16) short WH[1024 * 8];   // 16KB: [(kt*4+nt)*64 + lane][8]
    __shared__ __align__(16) short WL[1024 * 8];   // 16KB
    int t = threadIdx.x;
    int lane = t & 63;
    int wid = t >> 6;
    int q = lane & 15, g = lane >> 4;
    int tile = blockIdx.x << 6;

#pragma unroll
    for (int s = 0; s < 4; s++) {
        int sid = t + s * 256;
        int col = (((sid >> 6) & 3) << 4) + (sid & 15);
        int kb  = ((sid >> 8) << 5) + (((sid >> 4) & 3) << 3);
        union { short s[8]; uint4 u; } ph, pl;
#pragma unroll
        for (int i = 0; i < 8; i++) {
            float w = W[(kb + i) * HID + col];
            short h = f2bf(w);
            ph.s[i] = h;
            pl.s[i] = f2bf(w - bf2f(h));
        }
        *((uint4*)WH + sid) = ph.u;
        *((uint4*)WL + sid) = pl.u;
    }
    __syncthreads();

    int arow = tile + (wid << 4) + q;
    if (arow >= M) arow = M - 1;              // clamped rows discarded at store
    const float* ap = A + (long)arow * INDIM + (g << 3);
    f32x4 acc[4] = {};
#pragma unroll
    for (int kt = 0; kt < 4; kt++) {
        float4 x0 = *(const float4*)(ap + (kt << 5));
        float4 x1 = *(const float4*)(ap + (kt << 5) + 4);
        float xv[8] = {x0.x, x0.y, x0.z, x0.w, x1.x, x1.y, x1.z, x1.w};
        union { short s[8]; bf16x8 v; } ah, al;
#pragma unroll
        for (int i = 0; i < 8; i++) {
            short h = f2bf(xv[i]);
            ah.s[i] = h;
            al.s[i] = f2bf(xv[i] - bf2f(h));
        }
#pragma unroll
        for (int nt = 0; nt < 4; nt++) {
            int soff = ((((kt << 2) + nt) << 6) + lane) << 4;
            bf16x8 bh = *(const bf16x8*)((const char*)WH + soff);
            bf16x8 bl = *(const bf16x8*)((const char*)WL + soff);
            acc[nt] = __builtin_amdgcn_mfma_f32_16x16x32_bf16(ah.v, bh, acc[nt], 0, 0, 0);
            acc[nt] = __builtin_amdgcn_mfma_f32_16x16x32_bf16(ah.v, bl, acc[nt], 0, 0, 0);
            acc[nt] = __builtin_amdgcn_mfma_f32_16x16x32_bf16(al.v, bh, acc[nt], 0, 0, 0);
        }
    }
    // C/D layout: col = (nt<<4)+q, row = (g<<2)+reg. Scale by dinv, store bf16.
    int rbase = tile + (wid << 4) + (g << 2);
#pragma unroll
    for (int reg = 0; reg < 4; reg++) {
        int node = rbase + reg;
        if (node < M) {
            float di = dinv[node];
            __hip_bfloat16* out = C + ((long)node << 6) + q;
#pragma unroll
            for (int nt = 0; nt < 4; nt++)
                out[nt << 4] = __float2bfloat16(acc[nt][reg] * di);
        }
    }
}

#define LO16(u) __uint_as_float((u) << 16)
#define HI16(u) __uint_as_float((u) & 0xffff0000u)
// unpack one dwordx4 (8 bf16 features) into a[0..7], exact f32 math
#define ACC8(v)                                            \
    do {                                                   \
        a[0] += LO16((v).x); a[1] += HI16((v).x);          \
        a[2] += LO16((v).y); a[3] += HI16((v).y);          \
        a[4] += LO16((v).z); a[5] += HI16((v).z);          \
        a[6] += LO16((v).w); a[7] += HI16((v).w);          \
    } while (0)

// fused gather + next-layer GEMM, MFMA epilogue. Block = 4 waves = 64-node tile.
//  Phase B processes 32 edges per node per shot (2 idx dwordx4 + 8 data dwordx4 all
//  in flight): for Poisson(16) degree, ~all nodes take ZERO main iterations and ONE
//  clamped 32-edge block -> exposed latency per round = one idx+data chain.
//  Over-reads past e1 are clamped by VALUE (redirect to zeroed guard row hs[n]);
//  sorted_src over-read (<=31 ints) lands in the following workspace region.
template <bool HS_OUT>
__global__ __launch_bounds__(256) void fgather_k(void* __restrict__ outp,
                                                 const __hip_bfloat16* __restrict__ hs,
                                                 const float* __restrict__ dinv,
                                                 const float* __restrict__ biasA,
                                                 const float* __restrict__ Wn,
                                                 const float* __restrict__ biasB,
                                                 const int* __restrict__ rowbeg,
                                                 const int* __restrict__ rowend,
                                                 const int* __restrict__ sorted_src, int n) {
    __shared__ __align__(16) short WH[512 * 8];   // B-frags hi: [(kt*4+nt)*64 + lane][8]
    __shared__ __align__(16) short WL[512 * 8];   // B-frags lo
    __shared__ __align__(16) short RH[64 * 64];   // A-tile hi: [row][8 x 16B-block ^ row&7]
    __shared__ __align__(16) short RL[64 * 64];   // A-tile lo

    int t = threadIdx.x;
    int lane = t & 63;
    int wid = __builtin_amdgcn_readfirstlane(t >> 6);
    int q = lane & 15, g = lane >> 4;             // phase A/C coords
    int tile = blockIdx.x << 6;

    // ---- Phase A: stage W fragments (hi/lo bf16) ----
#pragma unroll
    for (int s = 0; s < 2; s++) {
        int sid = t + s * 256;
        int col = (((sid >> 6) & 3) << 4) + (sid & 15);
        int kb = ((sid >> 8) << 5) + (((sid >> 4) & 3) << 3);
        union { short s[8]; uint4 u; } ph, pl;
#pragma unroll
        for (int i = 0; i < 8; i++) {
            float w = Wn[(kb + i) * 64 + col];
            short h = f2bf(w);
            ph.s[i] = h;
            pl.s[i] = f2bf(w - bf2f(h));
        }
        *((uint4*)WH + sid) = ph.u;
        *((uint4*)WL + sid) = pl.u;
    }

    // ---- Phase B: aggregation, 2 nodes per wave-round ----
    int half = lane >> 5;                     // which node of the pair
    int g2 = (lane >> 3) & 3;                 // edge sub-stream 0..3
    int f8 = lane & 7;                        // feature octet 0..7
    int fo8 = f8 << 3;
    int rbv = 0, rev = 0;
    {
        int ndl = tile + (wid << 4) + (lane & 15);
        if (lane < 16 && ndl < n) { rbv = rowbeg[ndl]; rev = rowend[ndl]; }
    }
    __align__(16) float bb8[8];
    *(float4*)(bb8)     = *(const float4*)(biasA + fo8);
    *(float4*)(bb8 + 4) = *(const float4*)(biasA + fo8 + 4);

    for (int r = 0; r < 8; r++) {
        int row = (wid << 4) + (r << 1) + half;
        int nd = tile + row;
        int e0 = __shfl(rbv, row & 15);
        int e1 = __shfl(rev, row & 15);
        float a[8] = {0.f, 0.f, 0.f, 0.f, 0.f, 0.f, 0.f, 0.f};
        int e = e0;
        for (; e + 32 <= e1; e += 32) {       // 32 edges per node per iter
            u4u iv0 = *(const u4u*)(sorted_src + e + (g2 << 2));
            u4u iv1 = *(const u4u*)(sorted_src + e + 16 + (g2 << 2));
            uint4 v0 = *(const uint4*)(hs + (((int)iv0.x << 6) + fo8));
            uint4 v1 = *(const uint4*)(hs + (((int)iv0.y << 6) + fo8));
            uint4 v2 = *(const uint4*)(hs + (((int)iv0.z << 6) + fo8));
            uint4 v3 = *(const uint4*)(hs + (((int)iv0.w << 6) + fo8));
            uint4 v4 = *(const uint4*)(hs + (((int)iv1.x << 6) + fo8));
            uint4 v5 = *(const uint4*)(hs + (((int)iv1.y << 6) + fo8));
            uint4 v6 = *(const uint4*)(hs + (((int)iv1.z << 6) + fo8));
            uint4 v7 = *(const uint4*)(hs + (((int)iv1.w << 6) + fo8));
            ACC8(v0); ACC8(v1); ACC8(v2); ACC8(v3);
            ACC8(v4); ACC8(v5); ACC8(v6); ACC8(v7);
        }
        if (e < e1) {                         // one clamped 32-edge block
            int last = e1 - 1;
            int b0 = e + (g2 << 2);
            int b1 = b0 + 16;
            u4u iv0 = *(const u4u*)(sorted_src + b0);
            u4u iv1 = *(const u4u*)(sorted_src + b1);
            int i0 = (b0     <= last) ? (int)iv0.x : n;
            int i1 = (b0 + 1 <= last) ? (int)iv0.y : n;
            int i2 = (b0 + 2 <= last) ? (int)iv0.z : n;
            int i3 = (b0 + 3 <= last) ? (int)iv0.w : n;
            int i4 = (b1     <= last) ? (int)iv1.x : n;
            int i5 = (b1 + 1 <= last) ? (int)iv1.y : n;
            int i6 = (b1 + 2 <= last) ? (int)iv1.z : n;
            int i7 = (b1 + 3 <= last) ? (int)iv1.w : n;
            uint4 v0 = *(const uint4*)(hs + ((i0 << 6) + fo8));
            uint4 v1 = *(const uint4*)(hs + ((i1 << 6) + fo8));
            uint4 v2 = *(const uint4*)(hs + ((i2 << 6) + fo8));
            uint4 v3 = *(const uint4*)(hs + ((i3 << 6) + fo8));
            uint4 v4 = *(const uint4*)(hs + ((i4 << 6) + fo8));
            uint4 v5 = *(const uint4*)(hs + ((i5 << 6) + fo8));
            uint4 v6 = *(const uint4*)(hs + ((i6 << 6) + fo8));
            uint4 v7 = *(const uint4*)(hs + ((i7 << 6) + fo8));
            ACC8(v0); ACC8(v1); ACC8(v2); ACC8(v3);
            ACC8(v4); ACC8(v5); ACC8(v6); ACC8(v7);
        }
        // merge the 4 edge sub-streams (within each 32-lane half)
#pragma unroll
        for (int k = 0; k < 8; k++) a[k] += __shfl_xor(a[k], 8);
#pragma unroll
        for (int k = 0; k < 8; k++) a[k] += __shfl_xor(a[k], 16);
        // self-loop term (zero row for OOB)
        int snd = nd < n ? nd : n;
        uint4 sv = *(const uint4*)(hs + ((snd << 6) + fo8));
        ACC8(sv);
        float di = dinv[nd < n ? nd : 0];
        union { short s[8]; uint4 u; } ph, pl;
#pragma unroll
        for (int k = 0; k < 8; k++) {
            float rk = fmaxf(fmaf(di, a[k], bb8[k]), 0.f);
            short h = f2bf(rk);
            ph.s[k] = h;
            pl.s[k] = f2bf(rk - bf2f(h));
        }
        if (g2 == 0 && nd < n) {              // 8 lanes per half write the row
            int boff = row * 128 + ((f8 ^ (row & 7)) << 4);
            *(uint4*)((char*)RH + boff) = ph.u;
            *(uint4*)((char*)RL + boff) = pl.u;
        }
    }
    __syncthreads();                          // A-staging (and all RH/RL) -> Phase C

    // ---- Phase C: FC via MFMA ----
    f32x4 acc[4] = {};
#pragma unroll
    for (int kt = 0; kt < 2; kt++) {
        int arow = (wid << 4) + q;            // arow&7 == q&7 == write-side row&7
        int aoff = arow * 128 + ((((kt << 2) + g) ^ (q & 7)) << 4);
        bf16x8 ah = *(const bf16x8*)((const char*)RH + aoff);
        bf16x8 al = *(const bf16x8*)((const char*)RL + aoff);
#pragma unroll
        for (int nt = 0; nt < 4; nt++) {
            int soff = (((((kt << 2) + nt) << 6) + lane)) << 4;
            bf16x8 bh = *(const bf16x8*)((const char*)WH + soff);
            bf16x8 bl = *(const bf16x8*)((const char*)WL + soff);
            acc[nt] = __builtin_amdgcn_mfma_f32_16x16x32_bf16(ah, bh, acc[nt], 0, 0, 0);
            acc[nt] = __builtin_amdgcn_mfma_f32_16x16x32_bf16(ah, bl, acc[nt], 0, 0, 0);
            acc[nt] = __builtin_amdgcn_mfma_f32_16x16x32_bf16(al, bh, acc[nt], 0, 0, 0);
        }
    }

    // ---- epilogue: C[row = (g<<2)+reg][col = (nt<<4)+q] ----
    int rbase = tile + (wid << 4);
    if (HS_OUT) {
        __hip_bfloat16* out = (__hip_bfloat16*)outp;
#pragma unroll
        for (int reg = 0; reg < 4; reg++) {
            int node = rbase + (g << 2) + reg;
            if (node < n) {
                float di = dinv[node];
#pragma unroll
                for (int nt = 0; nt < 4; nt++)
                    out[(node << 6) + (nt << 4) + q] = __float2bfloat16(acc[nt][reg] * di);
            }
        }
    } else {
        float* out = (float*)outp;
        float bB[4];
#pragma unroll
        for (int nt = 0; nt < 4; nt++) bB[nt] = biasB[(nt << 4) + q];
#pragma unroll
        for (int reg = 0; reg < 4; reg++) {
            int node = rbase + (g << 2) + reg;
            if (node < n) {
#pragma unroll
                for (int nt = 0; nt < 4; nt++)
                    out[(node << 6) + (nt << 4) + q] = acc[nt][reg] + bB[nt];
            }
        }
    }
}

extern "C" void kernel_launch(void* const* d_in, const int* in_sizes, int n_in,
                              void* d_out, int out_size, void* d_ws, size_t ws_size,
                              hipStream_t stream) {
    const float* x   = (const float*)d_in[0];
    const int*   ei  = (const int*)d_in[1];
    const float* W1  = (const float*)d_in[2];
    const float* b1  = (const float*)d_in[3];
    const float* W2  = (const float*)d_in[4];
    const float* b2  = (const float*)d_in[5];
    const float* Wfc = (const float*)d_in[6];
    const float* bfc = (const float*)d_in[7];

    int N = in_sizes[0] / INDIM;
    int E = in_sizes[1] / 2;
    const int* src = ei;       // edge_index row 0
    const int* dst = ei + E;   // edge_index row 1
    int nb = (N + BK_NODES - 1) >> BK_SHIFT;          // 782 buckets
    int cap = (2 * E / nb + 63) & ~63;                // 2x mean bucket load
    if (cap < 4096) cap = 4096;

    char* ws = (char*)d_ws;
    auto alloc = [&](size_t bytes) {
        char* p = ws;
        ws += (bytes + 15) & ~(size_t)15;
        return p;
    };
    int*   rowbeg     = (int*)alloc(sizeof(int) * (size_t)N);
    int*   rowend     = (int*)alloc(sizeof(int) * (size_t)N);
    float* dinv       = (float*)alloc(sizeof(float) * (size_t)N);
    int*   cursor     = (int*)alloc(sizeof(int) * NBK_MAX);
    int*   sorted_src = (int*)alloc(sizeof(int) * (size_t)nb * cap);
    // big region: bucketed (int, nb*cap) first; later hs1+hs2 (bf16, 2*(N+1)*64,
    // each with a zeroed guard row at index N for clamped tail/OOB lanes).
    // Also provides the read-slack for fgather's 32-edge over-read of sorted_src.
    size_t big_bytes = sizeof(int) * (size_t)nb * cap;
    size_t hs_bytes  = sizeof(__hip_bfloat16) * 2 * (size_t)(N + 1) * HID;
    char*  big       = alloc(big_bytes > hs_bytes ? big_bytes : hs_bytes);
    int*   bucketed  = (int*)big;
    __hip_bfloat16* hs1 = (__hip_bfloat16*)big;
    __hip_bfloat16* hs2 = hs1 + (size_t)(N + 1) * HID;
    float* outp      = (float*)d_out;

    // build: memset + 2 dispatches
    hipMemsetAsync(cursor, 0, NBK_MAX * sizeof(int), stream);
    bpart_k<<<PB_BLOCKS, 256, 0, stream>>>(src, dst, cursor, bucketed, E, cap);
    bsort_k<<<nb, 256, 0, stream>>>(bucketed, cursor, rowbeg, rowend, sorted_src, dinv, N, cap);

    // zero guard rows (after bucketed is consumed; big region is reused as hs1/hs2)
    hipMemsetAsync(hs1 + (size_t)N * HID, 0, HID * sizeof(__hip_bfloat16), stream);
    hipMemsetAsync(hs2 + (size_t)N * HID, 0, HID * sizeof(__hip_bfloat16), stream);

    // compute: 3 dispatches
    gemm1_k<<<(N + 63) / 64, 256, 0, stream>>>(x, W1, dinv, hs1, N);
    fgather_k<true><<<(N + 63) / 64, 256, 0, stream>>>(hs2, hs1, dinv, b1, W2, nullptr,
                                                       rowbeg, rowend, sorted_src, N);
    fgather_k<false><<<(N + 63) / 64, 256, 0, stream>>>(outp, hs2, dinv, b2, Wfc, bfc,
                                                        rowbeg, rowend, sorted_src, N);
}